// Round 3
// baseline (793.605 us; speedup 1.0000x reference)
//
#include <hip/hip_runtime.h>
#include <hip/hip_bf16.h>

#define MAXD 32
#define MAXP 192
typedef __hip_bfloat16 bf16;

__device__ __forceinline__ float bf2f(bf16 v) { return __bfloat162float(v); }
__device__ __forceinline__ unsigned pk2(float x, float y) {
  bf16 bx = __float2bfloat16(x), by = __float2bfloat16(y);
  unsigned short ux, uy;
  __builtin_memcpy(&ux, &bx, 2);
  __builtin_memcpy(&uy, &by, 2);
  return (unsigned)ux | ((unsigned)uy << 16);
}

struct EdgeParams {
  const int* e[6];
  int E[6];
  int ebase[6];
  int nbase[6];
};

struct VSrc {
  const float* hf; const bf16* hh;
  const float* skf; const bf16* skh;
  const int* up;
  int nprev, Ch, Cs;
};

__device__ __forceinline__ float vloadf(const VSrc& s, int i, int c) {
  if (s.up) {
    if (c >= s.Ch) return s.skf[(long)i * s.Cs + (c - s.Ch)];
    if (i >= s.nprev) {
      int j = i - s.nprev;
      int u0 = s.up[2 * j], u1 = s.up[2 * j + 1];
      return 0.5f * (s.hf[(long)u0 * s.Ch + c] + s.hf[(long)u1 * s.Ch + c]);
    }
    return s.hf[(long)i * s.Ch + c];
  }
  return s.hf[(long)i * s.Ch + c];
}

__device__ __forceinline__ float2 vloadf2(const VSrc& s, int i, int c) {
  return make_float2(vloadf(s, i, c), vloadf(s, i, c + 1));
}

// ---------------- setup kernels ----------------
__global__ void k_fill(EdgeParams p, int* __restrict__ cnt, int2* __restrict__ ell, int ET) {
  for (int idx = blockIdx.x * blockDim.x + threadIdx.x; idx < ET; idx += gridDim.x * blockDim.x) {
    int l;
    if (idx < p.ebase[1]) l = 0;
    else if (idx < p.ebase[2]) l = 1;
    else if (idx < p.ebase[3]) l = 2;
    else if (idx < p.ebase[4]) l = 3;
    else if (idx < p.ebase[5]) l = 4;
    else l = 5;
    int e = idx - p.ebase[l];
    const int* epp = p.e[l];
    int row = epp[e];
    int col = epp[p.E[l] + e];
    int g = p.nbase[l] + row;
    int slot = atomicAdd(&cnt[g], 1);
    if (slot < MAXD) ell[g * MAXD + slot].x = col;
  }
}

__global__ void k_wfill(EdgeParams p, const int* __restrict__ cnt, int2* __restrict__ ell, int NT) {
  int total = NT * MAXD;
  for (int idx = blockIdx.x * blockDim.x + threadIdx.x; idx < total; idx += gridDim.x * blockDim.x) {
    int g = idx >> 5;
    int t = idx & (MAXD - 1);
    int dg = cnt[g];
    int d = dg < MAXD ? dg : MAXD;
    if (t < d) {
      int l;
      if (g < p.nbase[1]) l = 0;
      else if (g < p.nbase[2]) l = 1;
      else if (g < p.nbase[3]) l = 2;
      else if (g < p.nbase[4]) l = 3;
      else if (g < p.nbase[5]) l = 4;
      else l = 5;
      int c = ell[idx].x;
      int dc = cnt[p.nbase[l] + c];
      float w = (dc > 0) ? -(rsqrtf((float)dg) * rsqrtf((float)dc)) : 0.0f;
      ell[idx].y = __float_as_int(w);
    }
  }
}

// A^2 path list: for each row g, all (col_k, w_ij*w_jk) over j in N(g), k in N(j).
// Unmerged (duplicate cols just accumulate in the gather). One thread per
// (row, s1-slot); slots reserved via atomicAdd (order nondeterministic, sum is
// fp32-order-noise only — same as the atomic ELL1 fill that already passes).
__global__ void k_ell2(EdgeParams p, const int* __restrict__ cnt, const int2* __restrict__ ell,
                       int* __restrict__ cnt2, int2* __restrict__ ell2, int NT) {
  int total = NT * MAXD;
  for (int idx = blockIdx.x * blockDim.x + threadIdx.x; idx < total; idx += gridDim.x * blockDim.x) {
    int g = idx >> 5;
    int s1 = idx & (MAXD - 1);
    int d = cnt[g]; if (d > MAXD) d = MAXD;
    if (s1 >= d) continue;
    int l;
    if (g < p.nbase[1]) l = 0;
    else if (g < p.nbase[2]) l = 1;
    else if (g < p.nbase[3]) l = 2;
    else if (g < p.nbase[4]) l = 3;
    else if (g < p.nbase[5]) l = 4;
    else l = 5;
    int2 e1 = ell[(long)g * MAXD + s1];
    int j = e1.x;
    float w1 = __int_as_float(e1.y);
    int gj = p.nbase[l] + j;
    int dj = cnt[gj]; if (dj > MAXD) dj = MAXD;
    if (dj == 0) continue;
    int base = atomicAdd(&cnt2[g], dj);
    const int2* cj = ell + (long)gj * MAXD;
    for (int s2 = 0; s2 < dj; ++s2) {
      int slot = base + s2;
      if (slot < MAXP) {
        int2 e2 = cj[s2];
        ell2[(long)g * MAXP + slot] = make_int2(e2.x, __float_as_int(w1 * __int_as_float(e2.y)));
      }
    }
  }
}

// Merged setup: zero cnt+cnt2 + repack W[3][Cin][Cout] -> Wp[3][Cin/4][Cout][4] + x0 fp32->bf16.
struct WPack {
  const float* src[11];
  float* dst[11];
  int cin[11], cout[11], tot[11];
  const float* x0;
  bf16* x0h;
  int nx0;
};
__global__ void k_setup(WPack P, int TOT, int* __restrict__ cnt, int NT2) {
  int TALL = NT2 + TOT + P.nx0;
  for (int idx = blockIdx.x * blockDim.x + threadIdx.x; idx < TALL; idx += gridDim.x * blockDim.x) {
    if (idx < NT2) { cnt[idx] = 0; continue; }
    int off0 = idx - NT2;
    if (off0 >= TOT) {
      int j = off0 - TOT;
      P.x0h[j] = __float2bfloat16(P.x0[j]);
      continue;
    }
    int l = 0, off = off0;
    while (off >= P.tot[l]) { off -= P.tot[l]; ++l; }
    int cout = P.cout[l];
    int cinco = P.cin[l] * cout;
    int t = off / cinco;
    int rem = off - t * cinco;
    int k = rem / cout;
    int o = rem - k * cout;
    P.dst[l][((t * (P.cin[l] >> 2) + (k >> 2)) * cout + o) * 4 + (k & 3)] = P.src[l][off];
  }
}

// Materialize virtual upcat source into fp32 + bf16 flat arrays.
__global__ void k_xmat(VSrc src, float* __restrict__ Xf, bf16* __restrict__ Xh, int n, int Ctot) {
  int C2 = Ctot >> 1;
  int total = n * C2;
  for (int idx = blockIdx.x * blockDim.x + threadIdx.x; idx < total; idx += gridDim.x * blockDim.x) {
    int i = idx / C2;
    int c2 = idx - i * C2;
    float2 v = vloadf2(src, i, 2 * c2);
    long o = (long)i * Ctot + 2 * c2;
    *(unsigned*)(Xh + o) = pk2(v.x, v.y);
    *(float2*)(Xf + o) = v;
  }
}

// ELL gather: sum of w * Xh[col][k]. Index clamped to slot 0 past degree
// (slot 0 of a degree-0 row never read: loop body doesn't execute).
__device__ __forceinline__ float ell_gather(const int2* __restrict__ cols, int d,
                                            const bf16* __restrict__ Xh, int C, int k) {
  float a = 0.f;
  for (int t = 0; t < d; t += 8) {
    int ci[8]; float wj[8];
#pragma unroll
    for (int j = 0; j < 8; ++j) {
      int tt = t + j;
      int2 e = cols[(tt < d) ? tt : 0];
      ci[j] = e.x;
      wj[j] = (tt < d) ? __int_as_float(e.y) : 0.f;
    }
#pragma unroll
    for (int j = 0; j < 8; ++j)
      a += wj[j] * bf2f(Xh[(long)ci[j] * C + k]);
  }
  return a;
}

// ---------------- fused per-layer kernel ----------------
// One kernel per ChebConv layer: stages x (fp32), t1 = A x (ELL1 gather),
// t2 = 2*A^2 x - x (ELL2 gather) into LDS, then GEMM vs packed W.
// No intermediate global round-trips. (ROWS, CW) per round-2-proven tilings:
// small-n layers need max blocks / short chains (round-1 lesson).
template <int ROWS, int CW, int SMAX>
__global__ __launch_bounds__(256) void k_layer(
    const float* __restrict__ Xf, const bf16* __restrict__ Xh,
    const float4* __restrict__ Wp, const float* __restrict__ B,
    const int* __restrict__ cnt, const int2* __restrict__ ell,
    const int* __restrict__ cnt2, const int2* __restrict__ ell2,
    int nbase, int n, int Cin, int Cout,
    float* __restrict__ OUT, bf16* __restrict__ OUTh) {
  constexpr int RPW = (ROWS * CW) / 4;
  static_assert(RPW * (4 / CW) == ROWS, "bad ROWS/CW combo");

  __shared__ __align__(16) float sx[4][RPW][64];
  __shared__ __align__(16) float st1[4][RPW][64];
  __shared__ __align__(16) float st2[4][RPW][64];

  int tid = threadIdx.x;
  int w = tid >> 6;
  int lane = tid & 63;
  int rg = w / CW;
  int cw = w % CW;

  int colTiles = (Cout + 63) >> 6;
  int ct = blockIdx.x % colTiles;
  int rt = blockIdx.x / colTiles;
  int r0 = rt * ROWS + rg * RPW;
  int o = ct * 64 + lane;
  int oc = (o < Cout) ? o : (Cout - 1);
  int nch = (Cin + 63) >> 6;
  int KQ = Cin >> 2;

  float acc[RPW];
#pragma unroll
  for (int r = 0; r < RPW; ++r) acc[r] = 0.f;

  for (int cg = 0; cg < nch; cg += CW) {
    int c = cg + cw;
    bool act = c < nch;
    int k0 = c * 64;
    int kw = act ? ((Cin - k0 < 64) ? (Cin - k0) : 64) : 0;
    int k = k0 + lane;
    bool kv = act && (lane < kw);

#pragma unroll
    for (int rr = 0; rr < RPW; ++rr) {
      int i = r0 + rr;
      bool iv = i < n;
      float xv = 0.f, tv = 0.f, t2v = 0.f;
      if (kv && iv) {
        int g = nbase + i;
        xv = Xf[(long)i * Cin + k];
        int d = cnt[g]; if (d > MAXD) d = MAXD;
        tv = ell_gather(ell + (long)g * MAXD, d, Xh, Cin, k);
        int d2 = cnt2[g]; if (d2 > MAXP) d2 = MAXP;
        float a2 = ell_gather(ell2 + (long)g * MAXP, d2, Xh, Cin, k);
        t2v = 2.f * a2 - xv;
      }
      sx[w][rr][lane] = xv;
      st1[w][rr][lane] = tv;
      st2[w][rr][lane] = t2v;
    }
    __syncthreads();

    int kw4 = kw >> 2;
    for (int q = 0; q < kw4; ++q) {
      int kq = (k0 >> 2) + q;
      float4 w0 = Wp[(0 * KQ + kq) * Cout + oc];
      float4 w1 = Wp[(1 * KQ + kq) * Cout + oc];
      float4 w2 = Wp[(2 * KQ + kq) * Cout + oc];
#pragma unroll
      for (int rr = 0; rr < RPW; ++rr) {
        float4 xs = ((const float4*)sx[w][rr])[q];
        float4 t1s = ((const float4*)st1[w][rr])[q];
        float4 t2s = ((const float4*)st2[w][rr])[q];
        acc[rr] += w0.x * xs.x + w0.y * xs.y + w0.z * xs.z + w0.w * xs.w;
        acc[rr] += w1.x * t1s.x + w1.y * t1s.y + w1.z * t1s.z + w1.w * t1s.w;
        acc[rr] += w2.x * t2s.x + w2.y * t2s.y + w2.z * t2s.z + w2.w * t2s.w;
      }
    }
    __syncthreads();
  }

  if constexpr (SMAX) {
    float bb = (o < Cout) ? B[o] : 0.f;
#pragma unroll
    for (int rr = 0; rr < RPW; ++rr) {
      int i = r0 + rr;
      if (i < n) {
        float v = (o < Cout) ? (acc[rr] + bb) : -1e30f;
        float m = v;
        for (int s = 32; s > 0; s >>= 1) m = fmaxf(m, __shfl_xor(m, s));
        float e = (o < Cout) ? __expf(v - m) : 0.f;
        float sum = e;
        for (int s = 32; s > 0; s >>= 1) sum += __shfl_xor(sum, s);
        if (o < Cout) OUT[(long)i * Cout + o] = e / sum;
      }
    }
  } else if constexpr (CW == 1) {
    if (o < Cout) {
      float bb = B[oc];
#pragma unroll
      for (int rr = 0; rr < RPW; ++rr) {
        int i = r0 + rr;
        if (i < n) {
          float v = fmaxf(acc[rr] + bb, 0.f);
          long off = (long)i * Cout + o;
          OUT[off] = v;
          OUTh[off] = __float2bfloat16(v);
        }
      }
    }
  } else {
#pragma unroll
    for (int rr = 0; rr < RPW; ++rr) sx[w][rr][lane] = acc[rr];
    __syncthreads();
    if (cw == 0 && o < Cout) {
      float bb = B[oc];
#pragma unroll
      for (int rr = 0; rr < RPW; ++rr) {
        int i = r0 + rr;
        if (i < n) {
          float v = bb;
#pragma unroll
          for (int j = 0; j < CW; ++j) v += sx[rg * CW + j][rr][lane];
          v = fmaxf(v, 0.f);
          long off = (long)i * Cout + o;
          OUT[off] = v;
          OUTh[off] = __float2bfloat16(v);
        }
      }
    }
  }
}

// ---------------- launcher ----------------
extern "C" void kernel_launch(void* const* d_in, const int* in_sizes, int n_in,
                              void* d_out, int out_size, void* d_ws, size_t ws_size,
                              hipStream_t stream) {
  static const int NV[6] = {42, 162, 642, 2562, 10242, 40962};
  static const int NE[6] = {240, 960, 3840, 15360, 61440, 245760};
  const int NT = 54612;
  const int ET = 327600;

  EdgeParams ep;
  {
    int nb = 0, eb = 0;
    for (int l = 0; l < 6; ++l) {
      ep.e[l] = (const int*)d_in[1 + l];
      ep.E[l] = NE[l];
      ep.ebase[l] = eb;
      ep.nbase[l] = nb;
      eb += NE[l];
      nb += NV[l];
    }
  }
  const float* x0f = (const float*)d_in[0];
  const int* up[5];
  for (int i = 0; i < 5; ++i) up[i] = (const int*)d_in[7 + i];  // up2..up6
  const float *W[11], *Bb[11];
  for (int i = 0; i < 11; ++i) {
    W[i] = (const float*)d_in[12 + 2 * i];
    Bb[i] = (const float*)d_in[13 + 2 * i];
  }
  static const int LCI[11] = {4, 32, 64, 128, 256, 512, 768, 384, 192, 96, 36};
  static const int LCO[11] = {32, 64, 128, 256, 512, 512, 256, 128, 64, 32, 37};

  // ---- workspace carve (16B-aligned), ~136 MB of the >=268 MB ws ----
  char* p = (char*)d_ws;
  auto alloc_b = [&](size_t bytes) { void* r = (void*)p; p += (bytes + 15) & ~size_t(15); return r; };
  auto alloc_i = [&](size_t ne) { return (int*)alloc_b(ne * 4); };
  auto alloc_f = [&](size_t ne) { return (float*)alloc_b(ne * 4); };
  auto alloc_h = [&](size_t ne) { return (bf16*)alloc_b(ne * 2); };
  int* cnt = alloc_i((size_t)NT * 2);      // cnt | cnt2 contiguous (one zero range)
  int* cnt2 = cnt + NT;
  int2* ell = (int2*)alloc_b((size_t)NT * MAXD * 8);
  int2* ell2 = (int2*)alloc_b((size_t)NT * MAXP * 8);
  float* xf = alloc_f((size_t)40962 * 36);  // materialized upcat X (fp32)
  bf16* xh = alloc_h((size_t)40962 * 36);   // materialized upcat X (bf16)
  bf16* x0h = alloc_h((size_t)40962 * 4);
  float* wp[11];
  for (int i = 0; i < 11; ++i) wp[i] = alloc_f((size_t)3 * LCI[i] * LCO[i]);
  float *af[10]; bf16 *ah[10];
  const int an[10] = {40962, 10242, 2562, 642, 162, 42, 162, 642, 2562, 10242};
  const int ac[10] = {32, 64, 128, 256, 512, 512, 256, 128, 64, 32};
  for (int i = 0; i < 10; ++i) {
    af[i] = alloc_f((size_t)an[i] * ac[i]);
    ah[i] = alloc_h((size_t)an[i] * ac[i]);
  }

  {
    WPack P;
    int TOT = 0;
    for (int i = 0; i < 11; ++i) {
      P.src[i] = W[i];
      P.dst[i] = wp[i];
      P.cin[i] = LCI[i];
      P.cout[i] = LCO[i];
      P.tot[i] = 3 * LCI[i] * LCO[i];
      TOT += P.tot[i];
    }
    P.x0 = x0f; P.x0h = x0h; P.nx0 = 40962 * 4;
    k_setup<<<(2 * NT + TOT + P.nx0 + 255) / 256, 256, 0, stream>>>(P, TOT, cnt, 2 * NT);
  }
  k_fill<<<(ET + 255) / 256, 256, 0, stream>>>(ep, cnt, ell, ET);
  k_wfill<<<(NT * MAXD + 255) / 256, 256, 0, stream>>>(ep, cnt, ell, NT);
  k_ell2<<<(NT * MAXD + 255) / 256, 256, 0, stream>>>(ep, cnt, ell, cnt2, ell2, NT);

  auto upsrc = [](const float* hf, const bf16* hh, const float* skf, const bf16* skh,
                  const int* u, int nprev, int Ch, int Cs) {
    VSrc s{hf, hh, skf, skh, u, nprev, Ch, Cs}; return s;
  };

#define LAYER(RS, CWv, SM, Xfp, Xhp, lvl, n, Cin, Cout, Wq, Bp, OUT, OUTh)                       \
  {                                                                                              \
    int grid = (((Cout) + 63) / 64) * (((n) + (RS)-1) / (RS));                                   \
    k_layer<RS, CWv, SM><<<grid, 256, 0, stream>>>(Xfp, Xhp, (const float4*)(Wq), Bp,            \
                                                   cnt, ell, cnt2, ell2,                         \
                                                   ep.nbase[lvl], n, Cin, Cout, OUT, OUTh);      \
  }

  // ---- encoder ----
  LAYER(16, 1, 0, x0f, x0h, 5, 40962, 4, 32, wp[0], Bb[0], af[0], ah[0]);
  LAYER(16, 1, 0, af[0], ah[0], 4, 10242, 32, 64, wp[1], Bb[1], af[1], ah[1]);
  LAYER(4, 1, 0, af[1], ah[1], 3, 2562, 64, 128, wp[2], Bb[2], af[2], ah[2]);
  LAYER(2, 2, 0, af[2], ah[2], 2, 642, 128, 256, wp[3], Bb[3], af[3], ah[3]);
  LAYER(1, 4, 0, af[3], ah[3], 1, 162, 256, 512, wp[4], Bb[4], af[4], ah[4]);
  LAYER(1, 4, 0, af[4], ah[4], 0, 42, 512, 512, wp[5], Bb[5], af[5], ah[5]);
  // ---- decoder (upcat X materialized fp32+bf16, then fused layer) ----
  {
    VSrc s = upsrc(af[5], ah[5], af[3], ah[3], up[0], 42, 512, 256);
    k_xmat<<<(162 * 384 + 255) / 256, 256, 0, stream>>>(s, xf, xh, 162, 768);
    LAYER(1, 4, 0, xf, xh, 1, 162, 768, 256, wp[6], Bb[6], af[6], ah[6]);
  }
  {
    VSrc s = upsrc(af[6], ah[6], af[2], ah[2], up[1], 162, 256, 128);
    k_xmat<<<(642 * 192 + 255) / 256, 256, 0, stream>>>(s, xf, xh, 642, 384);
    LAYER(2, 4, 0, xf, xh, 2, 642, 384, 128, wp[7], Bb[7], af[7], ah[7]);
  }
  {
    VSrc s = upsrc(af[7], ah[7], af[1], ah[1], up[2], 642, 128, 64);
    k_xmat<<<(2562 * 96 + 255) / 256, 256, 0, stream>>>(s, xf, xh, 2562, 192);
    LAYER(2, 4, 0, xf, xh, 3, 2562, 192, 64, wp[8], Bb[8], af[8], ah[8]);
  }
  {
    VSrc s = upsrc(af[8], ah[8], af[0], ah[0], up[3], 2562, 64, 32);
    k_xmat<<<(10242 * 48 + 255) / 256, 256, 0, stream>>>(s, xf, xh, 10242, 96);
    LAYER(16, 1, 0, xf, xh, 4, 10242, 96, 32, wp[9], Bb[9], af[9], ah[9]);
  }
  {
    VSrc s = upsrc(af[9], ah[9], x0f, x0h, up[4], 10242, 32, 4);
    k_xmat<<<(40962 * 18 + 255) / 256, 256, 0, stream>>>(s, xf, xh, 40962, 36);
    LAYER(16, 1, 1, xf, xh, 5, 40962, 36, 37, wp[10], Bb[10], (float*)d_out, (bf16*)nullptr);
  }
}